// Round 11
// baseline (525.315 us; speedup 1.0000x reference)
//
#include <hip/hip_runtime.h>
#include <hip/hip_bf16.h>

#define NEG_SLOPE 0.2f
#define LOG2E 1.44269504f
#define EPB 8192      // edges per scatter block
#define MAXBUCK 400   // >= ceil(N/256)
#define CAP 9216      // pairs capacity per bucket (mean ~8184, 11-sigma pad)

typedef __attribute__((ext_vector_type(8))) short short8;
typedef __attribute__((ext_vector_type(4))) float f32x4;

__device__ __forceinline__ unsigned short f2bf(float x) {
    unsigned u = __float_as_uint(x);
    unsigned r = (u + 0x7FFFu + ((u >> 16) & 1u)) >> 16;  // RNE
    return (unsigned short)r;
}

__device__ __forceinline__ float fexp2(float x) {
    return __builtin_amdgcn_exp2f(x);  // v_exp_f32: 2^x
}

// ====== FUSED: layer-0 GEMM (MFMA, compute-bound) + edge scatter (latency) ==
// Independent work co-scheduled in one dispatch: blocks with role==scatter
// bucket edges into fixed-CAP segments; the rest run the 64-row GEMM tile.
// Interleave 1:4 (b%5==4 -> scatter) so both kinds are in flight together.
// bcnt is RELATIVE (zeroed by memset); pairs slot = b*CAP + base + r.
// csr_src later holds BYTE offsets (s<<7) into 128B-stride record tables.

template <int K>
__device__ __forceinline__ void gemm_body(
    int gb, const float* __restrict__ x, const float* __restrict__ W,
    const float* __restrict__ a_src, const float* __restrict__ a_dst,
    char* __restrict__ hrec, float* __restrict__ asb,
    float* __restrict__ adb, int N, char* smem) {
    constexpr int NT = 4;
    constexpr int KT = K / 32;
    short* Wf = (short*)smem;
    float* hL = (float*)smem;
    int tid = threadIdx.x;
    for (int f = tid; f < KT * NT * 64; f += 256) {
        int lane = f & 63;
        int ntk = f >> 6;
        int nt = ntk % NT, kt = ntk / NT;
        int q = lane >> 4, c = lane & 15;
        int n = nt * 16 + c;
        int k0 = kt * 32 + q * 8;
        short8 frag;
        #pragma unroll
        for (int j = 0; j < 8; ++j)
            frag[j] = (short)f2bf(W[(size_t)(k0 + j) * 64 + n]);
        *(short8*)&Wf[f * 8] = frag;
    }
    __syncthreads();
    int wave = tid >> 6, lane = tid & 63;
    int q = lane >> 4, c = lane & 15;
    int m0 = gb * 64 + wave * 16;
    int arow = m0 + c;
    int arl = arow < N ? arow : N - 1;
    f32x4 acc[NT] = {};
    for (int kt = 0; kt < KT; ++kt) {
        const float* xp = x + (size_t)arl * K + kt * 32 + q * 8;
        float4 a0 = *(const float4*)xp;
        float4 a1 = *(const float4*)(xp + 4);
        float av[8] = {a0.x, a0.y, a0.z, a0.w, a1.x, a1.y, a1.z, a1.w};
        short8 af;
        #pragma unroll
        for (int j = 0; j < 8; ++j) af[j] = (short)f2bf(av[j]);
        #pragma unroll
        for (int nt = 0; nt < NT; ++nt) {
            short8 bf = *(const short8*)&Wf[((kt * NT + nt) * 64 + lane) * 8];
            acc[nt] = __builtin_amdgcn_mfma_f32_16x16x32_bf16(af, bf, acc[nt],
                                                              0, 0, 0);
        }
    }
    __syncthreads();  // all waves done reading Wf; reuse as hL
    int lrow = wave * 16 + q * 4;
    #pragma unroll
    for (int nt = 0; nt < NT; ++nt)
        #pragma unroll
        for (int reg = 0; reg < 4; ++reg)
            hL[(lrow + reg) * 65 + nt * 16 + c] = acc[nt][reg];
    __syncthreads();
    #pragma unroll
    for (int it = 0; it < 2; ++it) {
        int id = it * 256 + tid;  // 0..511 = (node 0..63) x (head 0..7)
        int ln = id >> 3, hd = id & 7;
        int gn = gb * 64 + ln;
        if (gn >= N) continue;
        const float* hp = &hL[ln * 65 + hd * 8];
        float as = 0.f, ad = 0.f;
        float hv[8];
        #pragma unroll
        for (int j = 0; j < 8; ++j) {
            hv[j] = hp[j];
            as += hv[j] * a_src[hd * 8 + j];
            ad += hv[j] * a_dst[hd * 8 + j];
        }
        adb[gn * 8 + hd] = ad * LOG2E;
        asb[gn * 8 + hd] = as * LOG2E;
        unsigned short u[8];
        #pragma unroll
        for (int j = 0; j < 8; ++j) u[j] = f2bf(hv[j]);
        uint4 pk;
        pk.x = (unsigned)u[0] | ((unsigned)u[1] << 16);
        pk.y = (unsigned)u[2] | ((unsigned)u[3] << 16);
        pk.z = (unsigned)u[4] | ((unsigned)u[5] << 16);
        pk.w = (unsigned)u[6] | ((unsigned)u[7] << 16);
        *(uint4*)(hrec + (size_t)gn * 128 + hd * 16) = pk;
    }
}

__device__ __forceinline__ void scatter_body(
    int sb, const int* __restrict__ srcs, const int* __restrict__ dsts,
    int* __restrict__ bcnt, int* __restrict__ pairs, int E, int nbuck,
    char* smem) {
    int* lh = (int*)smem;
    int* lbase = lh + MAXBUCK;
    int t = threadIdx.x;
    for (int i = t; i < nbuck; i += 256) lh[i] = 0;
    __syncthreads();
    int base = sb * EPB;
    int cnt = E - base;
    if (cnt > EPB) cnt = EPB;
    int nq = cnt >> 2;
    const int4* d4p = (const int4*)(dsts + base);
    const int4* s4p = (const int4*)(srcs + base);
    for (int i = t; i < nq; i += 256) {
        int4 d = d4p[i];
        atomicAdd(&lh[d.x >> 8], 1);
        atomicAdd(&lh[d.y >> 8], 1);
        atomicAdd(&lh[d.z >> 8], 1);
        atomicAdd(&lh[d.w >> 8], 1);
    }
    for (int i = (nq << 2) + t; i < cnt; i += 256)
        atomicAdd(&lh[dsts[base + i] >> 8], 1);
    __syncthreads();
    for (int i = t; i < nbuck; i += 256) {
        int c = lh[i];
        lbase[i] = i * CAP + (c ? atomicAdd(&bcnt[i], c) : 0);
        lh[i] = 0;
    }
    __syncthreads();
    for (int i = t; i < nq; i += 256) {
        int4 d = d4p[i];
        int4 s = s4p[i];
        int b0 = d.x >> 8, b1 = d.y >> 8, b2 = d.z >> 8, b3 = d.w >> 8;
        int r0 = atomicAdd(&lh[b0], 1);
        int r1 = atomicAdd(&lh[b1], 1);
        int r2 = atomicAdd(&lh[b2], 1);
        int r3 = atomicAdd(&lh[b3], 1);
        pairs[lbase[b0] + r0] = (s.x << 8) | (d.x & 255);
        pairs[lbase[b1] + r1] = (s.y << 8) | (d.y & 255);
        pairs[lbase[b2] + r2] = (s.z << 8) | (d.z & 255);
        pairs[lbase[b3] + r3] = (s.w << 8) | (d.w & 255);
    }
    for (int i = (nq << 2) + t; i < cnt; i += 256) {
        int s = srcs[base + i], d = dsts[base + i];
        int r = atomicAdd(&lh[d >> 8], 1);
        pairs[lbase[d >> 8] + r] = (s << 8) | (d & 255);
    }
}

__global__ __launch_bounds__(256) void gemm0_scatter_k(
    const float* __restrict__ x, const float* __restrict__ W,
    const float* __restrict__ a_src, const float* __restrict__ a_dst,
    char* __restrict__ hrec, float* __restrict__ asb,
    float* __restrict__ adb, int N,
    const int* __restrict__ srcs, const int* __restrict__ dsts,
    int* __restrict__ bcnt, int* __restrict__ pairs, int E, int nbuck,
    int gGm, int gSc, int interleaved) {
    constexpr size_t WF_BYTES = (size_t)8 * 4 * 64 * 8 * sizeof(short);  // K=256
    constexpr size_t H_BYTES = (size_t)64 * 65 * sizeof(float);
    constexpr size_t SC_BYTES = (size_t)2 * MAXBUCK * sizeof(int);
    constexpr size_t SM = WF_BYTES > H_BYTES
                              ? (WF_BYTES > SC_BYTES ? WF_BYTES : SC_BYTES)
                              : (H_BYTES > SC_BYTES ? H_BYTES : SC_BYTES);
    __shared__ alignas(16) char smem[SM];
    int b = blockIdx.x;
    int isScat, idx;
    if (interleaved) {
        isScat = ((b % 5) == 4);
        idx = isScat ? (b / 5) : (b - (b + 1) / 5);
    } else {
        isScat = (b >= gGm);
        idx = isScat ? (b - gGm) : b;
    }
    if (isScat) {
        if (idx < gSc)
            scatter_body(idx, srcs, dsts, bcnt, pairs, E, nbuck, smem);
        return;
    }
    // gemm blocks with idx >= real tile count are fully guarded (gn<N)
    gemm_body<256>(idx, x, W, a_src, a_dst, hrec, asb, adb, N, smem);
}

// per-bucket: inline scan of bcnt -> e0g; LDS hist(256)+scan -> row_ptr +
// self-loop + sorted csr_src (byte offsets s<<7)
__global__ __launch_bounds__(512) void bucket_sort_k(
    const int* __restrict__ pairs, const int* __restrict__ bcnt,
    int* __restrict__ row_ptr, int* __restrict__ csr_src, int N, int Etot,
    int nbuck) {
    __shared__ int lh[256];
    __shared__ int sc[256];
    __shared__ int bsc[512];
    int b = blockIdx.x;
    int n0 = b << 8;
    int t = threadIdx.x;
    // block-local inclusive scan of bucket counts (nbuck <= 512)
    int v = (t < nbuck) ? bcnt[t] : 0;
    bsc[t] = v;
    __syncthreads();
    for (int off = 1; off < 512; off <<= 1) {
        int x = (t >= off) ? bsc[t - off] : 0;
        __syncthreads();
        bsc[t] += x;
        __syncthreads();
    }
    int e0g = (b > 0) ? bsc[b - 1] : 0;
    int myCnt = bsc[b] - e0g;
    if (t < 256) lh[t] = 0;
    __syncthreads();
    int e0c = b * CAP, e1c = e0c + myCnt;
    for (int e = e0c + t; e < e1c; e += 512)
        atomicAdd(&lh[pairs[e] & 255], 1);
    __syncthreads();
    if (t < 256) sc[t] = lh[t];
    __syncthreads();
    for (int off = 1; off < 256; off <<= 1) {
        int x = (t < 256 && t >= off) ? sc[t - off] : 0;
        __syncthreads();
        if (t < 256) sc[t] += x;
        __syncthreads();
    }
    if (t < 256) {
        int cntv = lh[t];
        int excl = sc[t] - cntv;
        int n = n0 + t;
        int rp = e0g + n0 + t + excl;  // edges before n + self-loops before n
        if (n < N) {
            row_ptr[n] = rp;
            csr_src[rp] = n << 7;  // self-loop at slot 0 (byte offset)
        }
        lh[t] = rp + 1;  // cursor
    }
    __syncthreads();
    for (int e = e0c + t; e < e1c; e += 512) {
        int p = pairs[e];
        int pos = atomicAdd(&lh[p & 255], 1);
        csr_src[pos] = (p >> 8) << 7;  // s<<7
    }
    if (b == 0 && t == 0) row_ptr[N] = Etot;
}

// ====== standalone GEMM (layer 1, K=64) ======

__global__ __launch_bounds__(256) void gemm_pack8_k64(
    const float* __restrict__ x, const float* __restrict__ W,
    const float* __restrict__ a_src, const float* __restrict__ a_dst,
    char* __restrict__ hrec, float* __restrict__ asb,
    float* __restrict__ adb, int N) {
    constexpr size_t WF_BYTES = (size_t)2 * 4 * 64 * 8 * sizeof(short);
    constexpr size_t H_BYTES = (size_t)64 * 65 * sizeof(float);
    __shared__ alignas(16) char smem[WF_BYTES > H_BYTES ? WF_BYTES : H_BYTES];
    gemm_body<64>(blockIdx.x, x, W, a_src, a_dst, hrec, asb, adb, N, smem);
}

// ====== fused MFMA GEMM + pack40 (layer 2): 128 B records, as at +80 ======

__global__ __launch_bounds__(256) void gemm_pack40_k(
    const float* __restrict__ x, const float* __restrict__ W,
    const float* __restrict__ a_src, const float* __restrict__ a_dst,
    char* __restrict__ rec40, float* __restrict__ adb, int N) {
    constexpr int K = 64, NT = 3, KT = 2;
    constexpr size_t WF_BYTES = (size_t)KT * NT * 64 * 8 * sizeof(short);
    constexpr size_t H_BYTES = (size_t)64 * 41 * sizeof(float);
    __shared__ alignas(16) char smem[WF_BYTES > H_BYTES ? WF_BYTES : H_BYTES];
    short* Wf = (short*)smem;
    float* hL = (float*)smem;
    int tid = threadIdx.x;
    for (int f = tid; f < KT * NT * 64; f += 256) {
        int lane = f & 63;
        int ntk = f >> 6;
        int nt = ntk % NT, kt = ntk / NT;
        int q = lane >> 4, c = lane & 15;
        int n = nt * 16 + c;
        int k0 = kt * 32 + q * 8;
        short8 frag;
        #pragma unroll
        for (int j = 0; j < 8; ++j) {
            float v = (n < 40) ? W[(size_t)(k0 + j) * 40 + n] : 0.f;
            frag[j] = (short)f2bf(v);
        }
        *(short8*)&Wf[f * 8] = frag;
    }
    __syncthreads();
    int wave = tid >> 6, lane = tid & 63;
    int q = lane >> 4, c = lane & 15;
    int m0 = blockIdx.x * 64 + wave * 16;
    int arow = m0 + c;
    int arl = arow < N ? arow : N - 1;
    f32x4 acc[NT] = {};
    for (int kt = 0; kt < KT; ++kt) {
        const float* xp = x + (size_t)arl * K + kt * 32 + q * 8;
        float4 a0 = *(const float4*)xp;
        float4 a1 = *(const float4*)(xp + 4);
        float av[8] = {a0.x, a0.y, a0.z, a0.w, a1.x, a1.y, a1.z, a1.w};
        short8 af;
        #pragma unroll
        for (int j = 0; j < 8; ++j) af[j] = (short)f2bf(av[j]);
        #pragma unroll
        for (int nt = 0; nt < NT; ++nt) {
            short8 bf = *(const short8*)&Wf[((kt * NT + nt) * 64 + lane) * 8];
            acc[nt] = __builtin_amdgcn_mfma_f32_16x16x32_bf16(af, bf, acc[nt],
                                                              0, 0, 0);
        }
    }
    __syncthreads();
    int lrow = wave * 16 + q * 4;
    #pragma unroll
    for (int nt = 0; nt < NT; ++nt) {
        int n = nt * 16 + c;
        if (n >= 40) continue;
        #pragma unroll
        for (int reg = 0; reg < 4; ++reg)
            hL[(lrow + reg) * 41 + n] = acc[nt][reg];
    }
    __syncthreads();
    // 4 threads per node compute pas/pad
    int ln = tid >> 2, sub = tid & 3;
    int gn = blockIdx.x * 64 + ln;
    float pas = 0.f, pad = 0.f;
    if (gn < N) {
        for (int j = sub; j < 40; j += 4) {
            float hv = hL[ln * 41 + j];
            pas += hv * a_src[j];
            pad += hv * a_dst[j];
        }
    }
    pas += __shfl_xor(pas, 1); pas += __shfl_xor(pas, 2);
    pad += __shfl_xor(pad, 1); pad += __shfl_xor(pad, 2);
    if (gn < N && sub == 0) {
        *(float*)(rec40 + (size_t)gn * 128 + 80) = pas * LOG2E;
        adb[gn] = pad * LOG2E;
    }
    // write bf16 h, stride 128 B
    for (int i = tid; i < 64 * 40; i += 256) {
        int n2 = i / 40, ch = i % 40;
        int g2 = blockIdx.x * 64 + n2;
        if (g2 < N)
            *(unsigned short*)(rec40 + (size_t)g2 * 128 + ch * 2) =
                f2bf(hL[n2 * 41 + ch]);
    }
}

// ======= aggr64: 8 edges per gather (16 B/lane dwordx4) ====================
// Lane layout in fma phase: g=lane>>3 picks edge j+g, head=lane&7 picks the
// 16B head chunk. Weights in LDS [head*68+edge] (<=2-way banks, 0 conflicts).
// Final combine: shfl_xor over masks 8/16/32. Padded edges have w==0.

#define G64(SUF, JB)                                                          \
    int sv##SUF = __builtin_amdgcn_ds_bpermute((JB) * 4 + g4, sv);            \
    float w##SUF = wb[(JB) + wofs];                                           \
    uint4 hv##SUF =                                                           \
        *(const uint4*)(gbase + (size_t)(unsigned)sv##SUF + hoff);

#define FMA8(SUF, LS)                                                         \
    LS;                                                                       \
    acc0 = fmaf(w##SUF, __uint_as_float(hv##SUF.x << 16), acc0);              \
    acc1 = fmaf(w##SUF, __uint_as_float(hv##SUF.x & 0xFFFF0000u), acc1);      \
    acc2 = fmaf(w##SUF, __uint_as_float(hv##SUF.y << 16), acc2);              \
    acc3 = fmaf(w##SUF, __uint_as_float(hv##SUF.y & 0xFFFF0000u), acc3);      \
    acc4 = fmaf(w##SUF, __uint_as_float(hv##SUF.z << 16), acc4);              \
    acc5 = fmaf(w##SUF, __uint_as_float(hv##SUF.z & 0xFFFF0000u), acc5);      \
    acc6 = fmaf(w##SUF, __uint_as_float(hv##SUF.w << 16), acc6);              \
    acc7 = fmaf(w##SUF, __uint_as_float(hv##SUF.w & 0xFFFF0000u), acc7);

__global__ __launch_bounds__(256) void aggr64_k(
    const char* __restrict__ hrec, const float* __restrict__ asb,
    const float* __restrict__ adb, const int* __restrict__ row_ptr,
    const int* __restrict__ csr_src, const float* __restrict__ bias,
    float* __restrict__ out, int N) {
    __shared__ float wlds[4 * 544];  // 4 waves x 8 heads x 68
    int wave = threadIdx.x >> 6;
    int node = blockIdx.x * 4 + wave;
    if (node >= N) return;
    int lane = threadIdx.x & 63;
    const char* gbase = hrec;
    float* wb = wlds + wave * 544;
    int g4 = (lane >> 3) * 4;                      // bpermute byte addr part
    int hoff = (lane & 7) * 16;                    // byte offset in record
    int wofs = (lane & 7) * 68 + (lane >> 3);      // w read offset
    int beg = row_ptr[node], end = row_ptr[node + 1];
    float4 adv0 = *(const float4*)(adb + (size_t)node * 8);
    float4 adv1 = *(const float4*)(adb + (size_t)node * 8 + 4);
    float acc0 = 0.f, acc1 = 0.f, acc2 = 0.f, acc3 = 0.f;
    float acc4 = 0.f, acc5 = 0.f, acc6 = 0.f, acc7 = 0.f;
    float lpart = 0.f;
    for (int i0 = beg; i0 < end; i0 += 64) {
        int tail = end - i0;
        int sv = csr_src[i0 + (lane < tail ? lane : 0)];  // byte offset s<<7
        int cnt = tail < 64 ? tail : 64;
        // ---- weight phase: this lane's edge, all 8 heads ----
        {
            const float* asp =
                (const float*)((const char*)asb + (((unsigned)sv) >> 2));
            float4 s0 = *(const float4*)asp;
            float4 s1 = *(const float4*)(asp + 4);
            float w0 = s0.x + adv0.x; w0 = fmaxf(w0, NEG_SLOPE * w0); w0 = fexp2(w0);
            float w1 = s0.y + adv0.y; w1 = fmaxf(w1, NEG_SLOPE * w1); w1 = fexp2(w1);
            float w2 = s0.z + adv0.z; w2 = fmaxf(w2, NEG_SLOPE * w2); w2 = fexp2(w2);
            float w3 = s0.w + adv0.w; w3 = fmaxf(w3, NEG_SLOPE * w3); w3 = fexp2(w3);
            float w4 = s1.x + adv1.x; w4 = fmaxf(w4, NEG_SLOPE * w4); w4 = fexp2(w4);
            float w5 = s1.y + adv1.y; w5 = fmaxf(w5, NEG_SLOPE * w5); w5 = fexp2(w5);
            float w6 = s1.z + adv1.z; w6 = fmaxf(w6, NEG_SLOPE * w6); w6 = fexp2(w6);
            float w7 = s1.w + adv1.w; w7 = fmaxf(w7, NEG_SLOPE * w7); w7 = fexp2(w7);
            if (lane >= cnt) {  // zero-pad
                w0 = 0.f; w1 = 0.f; w2 = 0.f; w3 = 0.f;
                w4 = 0.f; w5 = 0.f; w6 = 0.f; w7 = 0.f;
            }
            wb[lane]          = w0;
            wb[68 + lane]     = w1;
            wb[2 * 68 + lane] = w2;
            wb[3 * 68 + lane] = w3;
            wb[4 * 68 + lane] = w4;
            wb[5 * 68 + lane] = w5;
            wb[6 * 68 + lane] = w6;
            wb[7 * 68 + lane] = w7;
        }
        // ---- fma phase: 8 edges per gather (lpart += w, per subset) ----
        int j = 0;
        for (; j + 32 <= cnt; j += 32) {
            G64(A, j) G64(B, j + 8) G64(C, j + 16) G64(D, j + 24)
            FMA8(A, lpart += wA) FMA8(B, lpart += wB)
            FMA8(C, lpart += wC) FMA8(D, lpart += wD)
        }
        for (; j < cnt; j += 8) {
            G64(A, j)
            FMA8(A, lpart += wA)
        }
    }
    // combine the 8 edge-subsets per head (lanes differing in bits 3..5)
    #pragma unroll
    for (int m = 8; m <= 32; m <<= 1) {
        acc0 += __shfl_xor(acc0, m);
        acc1 += __shfl_xor(acc1, m);
        acc2 += __shfl_xor(acc2, m);
        acc3 += __shfl_xor(acc3, m);
        acc4 += __shfl_xor(acc4, m);
        acc5 += __shfl_xor(acc5, m);
        acc6 += __shfl_xor(acc6, m);
        acc7 += __shfl_xor(acc7, m);
        lpart += __shfl_xor(lpart, m);
    }
    if (lane < 8) {  // lane = head; writes channels head*8..head*8+7
        float denom = lpart + 1e-16f;
        const float4 b0 = *(const float4*)(bias + lane * 8);
        const float4 b1 = *(const float4*)(bias + lane * 8 + 4);
        float4 o0, o1;
        o0.x = acc0 / denom + b0.x;
        o0.y = acc1 / denom + b0.y;
        o0.z = acc2 / denom + b0.z;
        o0.w = acc3 / denom + b0.w;
        o1.x = acc4 / denom + b1.x;
        o1.y = acc5 / denom + b1.y;
        o1.z = acc6 / denom + b1.z;
        o1.w = acc7 / denom + b1.w;
        float* op = out + (size_t)node * 64 + lane * 8;
        *(float4*)op = o0;
        *(float4*)(op + 4) = o1;
    }
}

// ======= aggr40: 8 edges per gather; 5 active 8-ch chunks ==================
// l comes from the weight phase (per-lane own edge, full-wave reduce).

#define G40(SUF, JB)                                                          \
    int sv##SUF = __builtin_amdgcn_ds_bpermute((JB) * 4 + g4, sv);            \
    float w##SUF = wb[(JB) + gof];                                           \
    uint4 hv##SUF =                                                          \
        *(const uint4*)(gbase + (size_t)(unsigned)sv##SUF + hoff);

__global__ __launch_bounds__(256) void aggr40_k(
    const char* __restrict__ rec40, const float* __restrict__ adb,
    const int* __restrict__ row_ptr, const int* __restrict__ csr_src,
    const float* __restrict__ bias, float* __restrict__ out, int N) {
    __shared__ float wlds[4 * 104];  // per wave: 64 w + 40 epi
    int wave = threadIdx.x >> 6;
    int node = blockIdx.x * 4 + wave;
    if (node >= N) return;
    int lane = threadIdx.x & 63;
    const char* gbase = rec40;
    float* wb = wlds + wave * 104;
    float* epi = wb + 64;
    int g4 = (lane >> 3) * 4;
    int sub = lane & 7;
    int hoff = (sub < 5 ? sub : 0) * 16;
    int gof = lane >> 3;
    int beg = row_ptr[node], end = row_ptr[node + 1];
    float ad = adb[node];
    float acc0 = 0.f, acc1 = 0.f, acc2 = 0.f, acc3 = 0.f;
    float acc4 = 0.f, acc5 = 0.f, acc6 = 0.f, acc7 = 0.f;
    float lpart = 0.f;
    for (int i0 = beg; i0 < end; i0 += 64) {
        int tail = end - i0;
        int sv = csr_src[i0 + (lane < tail ? lane : 0)];  // byte offset s<<7
        int cnt = tail < 64 ? tail : 64;
        // ---- weight phase: lane computes its own edge's weight ----
        float as = *(const float*)(rec40 + (size_t)(unsigned)sv + 80);
        float v = as + ad;
        v = fmaxf(v, NEG_SLOPE * v);
        float wv = fexp2(v);
        wv = (lane < cnt) ? wv : 0.f;
        lpart += wv;
        wb[lane] = wv;
        // ---- fma phase: 8 edges per gather (w already counted in lpart) ----
        int j = 0;
        for (; j + 32 <= cnt; j += 32) {
            G40(A, j) G40(B, j + 8) G40(C, j + 16) G40(D, j + 24)
            FMA8(A, ) FMA8(B, ) FMA8(C, ) FMA8(D, )
        }
        for (; j < cnt; j += 8) {
            G40(A, j)
            FMA8(A, )
        }
    }
    // reduce acc over the 8 edge-subsets (lanes sharing sub)
    #pragma unroll
    for (int m = 8; m <= 32; m <<= 1) {
        acc0 += __shfl_xor(acc0, m);
        acc1 += __shfl_xor(acc1, m);
        acc2 += __shfl_xor(acc2, m);
        acc3 += __shfl_xor(acc3, m);
        acc4 += __shfl_xor(acc4, m);
        acc5 += __shfl_xor(acc5, m);
        acc6 += __shfl_xor(acc6, m);
        acc7 += __shfl_xor(acc7, m);
    }
    // l: full-wave reduce of weight-phase partials
    #pragma unroll
    for (int off = 32; off > 0; off >>= 1) lpart += __shfl_xor(lpart, off);
    float l = lpart;
    // redistribute: lanes 0..4 (g==0, sub<5) hold sums for channels sub*8+k
    if (lane < 5) {
        *(float4*)&epi[lane * 8] = make_float4(acc0, acc1, acc2, acc3);
        *(float4*)&epi[lane * 8 + 4] = make_float4(acc4, acc5, acc6, acc7);
    }
    float accv = (lane < 40) ? epi[lane] : 0.f;
    // fused bias + log_softmax over the 40 class lanes
    float val = accv / (l + 1e-16f) + ((lane < 40) ? bias[lane] : 0.f);
    float mval = (lane < 40) ? val : -1e30f;
    #pragma unroll
    for (int off = 32; off > 0; off >>= 1)
        mval = fmaxf(mval, __shfl_xor(mval, off));
    float ex = (lane < 40) ? __expf(val - mval) : 0.f;
    #pragma unroll
    for (int off = 32; off > 0; off >>= 1) ex += __shfl_xor(ex, off);
    if (lane < 40)
        out[(size_t)node * 40 + lane] = val - mval - __logf(ex);
}

// =================== launch ===================

extern "C" void kernel_launch(void* const* d_in, const int* in_sizes, int n_in,
                              void* d_out, int out_size, void* d_ws,
                              size_t ws_size, hipStream_t stream) {
    const float* features = (const float*)d_in[0];
    const int* edge_index = (const int*)d_in[1];
    const float* W0 = (const float*)d_in[2];
    const float* as0 = (const float*)d_in[3];
    const float* ad0 = (const float*)d_in[4];
    const float* b0 = (const float*)d_in[5];
    const float* W1 = (const float*)d_in[6];
    const float* as1 = (const float*)d_in[7];
    const float* ad1 = (const float*)d_in[8];
    const float* b1 = (const float*)d_in[9];
    const float* W2 = (const float*)d_in[10];
    const float* as2 = (const float*)d_in[11];
    const float* ad2 = (const float*)d_in[12];
    const float* b2 = (const float*)d_in[13];

    int N = in_sizes[0] / 256;
    int E = in_sizes[1] / 2;
    int Etot = E + N;
    int nbuck = (N + 255) >> 8;  // 256-node buckets (<= MAXBUCK)
    const int* srcs = edge_index;
    const int* dsts = edge_index + E;

    // workspace layout
    float* ws = (float*)d_ws;
    float* Hbuf = ws;                              // N*64 floats (pairs scratch)
    float* Abuf = Hbuf + (size_t)N * 64;           // N*64 floats
    float* adb  = Abuf + (size_t)N * 64;           // N*8
    float* asb  = adb + (size_t)N * 8;             // N*8
    char* hrec  = (char*)(asb + (size_t)N * 8);    // N*128 bytes
    int* row_ptr = (int*)(hrec + (size_t)N * 128); // N+1
    int* bcnt    = row_ptr + (N + 2);              // MAXBUCK
    int* csr_src = bcnt + MAXBUCK;                 // Etot
    int* pairs   = (int*)Hbuf;                     // nbuck*CAP <= N*64

    const int B = 256;
    int gAg = (N + 3) / 4;
    int gGm = (N + 63) / 64;
    int gSc = (E + EPB - 1) / EPB;
    int interleaved = (4 * gSc >= gGm) ? 1 : 0;
    int gFuse = interleaved ? 5 * gSc : gGm + gSc;

    // ---------- memset bucket counters ----------
    (void)hipMemsetAsync(bcnt, 0, MAXBUCK * 4, stream);

    // ---------- FUSED: layer-0 GEMM || edge scatter ----------
    gemm0_scatter_k<<<gFuse, B, 0, stream>>>(features, W0, as0, ad0, hrec,
                                             asb, adb, N, srcs, dsts, bcnt,
                                             pairs, E, nbuck, gGm, gSc,
                                             interleaved);

    // ---------- bucket sort (inline scan) ----------
    bucket_sort_k<<<nbuck, 512, 0, stream>>>(pairs, bcnt, row_ptr, csr_src,
                                             N, Etot, nbuck);

    // ---------------- layer 0 aggregate ----------------
    aggr64_k<<<gAg, B, 0, stream>>>(hrec, asb, adb, row_ptr, csr_src, b0,
                                    Abuf, N);

    // ---------------- layer 1 ----------------
    gemm_pack8_k64<<<gGm, B, 0, stream>>>(Abuf, W1, as1, ad1, hrec, asb,
                                          adb, N);
    aggr64_k<<<gAg, B, 0, stream>>>(hrec, asb, adb, row_ptr, csr_src, b1,
                                    Abuf, N);

    // ---------------- layer 2 ----------------
    gemm_pack40_k<<<gGm, B, 0, stream>>>(Abuf, W2, as2, ad2, hrec, adb, N);
    aggr40_k<<<gAg, B, 0, stream>>>(hrec, adb, row_ptr, csr_src, b2,
                                    (float*)d_out, N);
}

// Round 12
// 522.926 us; speedup vs baseline: 1.0046x; 1.0046x over previous
//
#include <hip/hip_runtime.h>
#include <hip/hip_bf16.h>

#define NEG_SLOPE 0.2f
#define LOG2E 1.44269504f
#define EPB 8192      // edges per scatter block
#define MAXBUCK 400   // >= ceil(N/256)
#define CAP 9216      // pairs capacity per bucket (mean ~8184, 11-sigma pad)

typedef __attribute__((ext_vector_type(8))) short short8;
typedef __attribute__((ext_vector_type(4))) float f32x4;

__device__ __forceinline__ unsigned short f2bf(float x) {
    unsigned u = __float_as_uint(x);
    unsigned r = (u + 0x7FFFu + ((u >> 16) & 1u)) >> 16;  // RNE
    return (unsigned short)r;
}

__device__ __forceinline__ float fexp2(float x) {
    return __builtin_amdgcn_exp2f(x);  // v_exp_f32: 2^x
}

// ===== CSR build: 256-node buckets, fixed-CAP segments, self-hist scatter ===
// csr_src holds BYTE offsets (s<<7) into the 128B-stride record tables.

__global__ __launch_bounds__(256) void binit_k(int* __restrict__ bcurE,
                                               int nbuck) {
    int b = blockIdx.x * 256 + threadIdx.x;
    if (b < nbuck) bcurE[b] = b * CAP;
}

// self-hist scatter into fixed-CAP bucket segments (bucket = d>>8)
// 1024 threads: latency-bound kernel, max wave residency.
__global__ __launch_bounds__(1024) void bscatter_k(
    const int* __restrict__ srcs, const int* __restrict__ dsts,
    int* __restrict__ bcurE, int* __restrict__ pairs, int E, int nbuck) {
    __shared__ int lh[MAXBUCK];
    __shared__ int lbase[MAXBUCK];
    int t = threadIdx.x;
    if (t < nbuck) lh[t] = 0;
    __syncthreads();
    int base = blockIdx.x * EPB;
    int cnt = E - base;
    if (cnt > EPB) cnt = EPB;
    int nq = cnt >> 2;
    const int4* d4p = (const int4*)(dsts + base);
    const int4* s4p = (const int4*)(srcs + base);
    for (int i = t; i < nq; i += 1024) {
        int4 d = d4p[i];
        atomicAdd(&lh[d.x >> 8], 1);
        atomicAdd(&lh[d.y >> 8], 1);
        atomicAdd(&lh[d.z >> 8], 1);
        atomicAdd(&lh[d.w >> 8], 1);
    }
    for (int i = (nq << 2) + t; i < cnt; i += 1024)
        atomicAdd(&lh[dsts[base + i] >> 8], 1);
    __syncthreads();
    if (t < nbuck) {
        int c = lh[t];
        lbase[t] = c ? atomicAdd(&bcurE[t], c) : 0;
        lh[t] = 0;
    }
    __syncthreads();
    for (int i = t; i < nq; i += 1024) {
        int4 d = d4p[i];
        int4 s = s4p[i];
        int b0 = d.x >> 8, b1 = d.y >> 8, b2 = d.z >> 8, b3 = d.w >> 8;
        int r0 = atomicAdd(&lh[b0], 1);
        int r1 = atomicAdd(&lh[b1], 1);
        int r2 = atomicAdd(&lh[b2], 1);
        int r3 = atomicAdd(&lh[b3], 1);
        pairs[lbase[b0] + r0] = (s.x << 8) | (d.x & 255);
        pairs[lbase[b1] + r1] = (s.y << 8) | (d.y & 255);
        pairs[lbase[b2] + r2] = (s.z << 8) | (d.z & 255);
        pairs[lbase[b3] + r3] = (s.w << 8) | (d.w & 255);
    }
    for (int i = (nq << 2) + t; i < cnt; i += 1024) {
        int s = srcs[base + i], d = dsts[base + i];
        int r = atomicAdd(&lh[d >> 8], 1);
        pairs[lbase[d >> 8] + r] = (s << 8) | (d & 255);
    }
}

// 1-block exclusive scan of bucket counts (bcurE[b]-b*CAP) -> bstart
__global__ __launch_bounds__(512) void bscan_k(
    const int* __restrict__ bcurE, int* __restrict__ bstart, int nbuck) {
    __shared__ int csum[512];
    int t = threadIdx.x;
    int v = (t < nbuck) ? bcurE[t] - t * CAP : 0;
    csum[t] = v;
    __syncthreads();
    for (int off = 1; off < 512; off <<= 1) {
        int x = (t >= off) ? csum[t - off] : 0;
        __syncthreads();
        csum[t] += x;
        __syncthreads();
    }
    if (t < nbuck) bstart[t] = csum[t] - v;
}

// per-bucket: LDS hist(256) + scan -> row_ptr + self-loop + sorted csr_src
// 1024 threads: two latency-bound passes over ~8K pairs each.
__global__ __launch_bounds__(1024) void bucket_sort_k(
    const int* __restrict__ pairs, const int* __restrict__ bcurE,
    const int* __restrict__ bstart, int* __restrict__ row_ptr,
    int* __restrict__ csr_src, int N, int Etot) {
    __shared__ int lh[256];
    __shared__ int sc[256];
    int b = blockIdx.x;
    int n0 = b << 8;
    int t = threadIdx.x;
    if (t < 256) lh[t] = 0;
    __syncthreads();
    int e0c = b * CAP, e1c = bcurE[b];
    for (int e = e0c + t; e < e1c; e += 1024)
        atomicAdd(&lh[pairs[e] & 255], 1);
    __syncthreads();
    if (t < 256) sc[t] = lh[t];
    __syncthreads();
    for (int off = 1; off < 256; off <<= 1) {
        int x = (t < 256 && t >= off) ? sc[t - off] : 0;
        __syncthreads();
        if (t < 256) sc[t] += x;
        __syncthreads();
    }
    int e0g = bstart[b];
    if (t < 256) {
        int cntv = lh[t];
        int excl = sc[t] - cntv;
        int n = n0 + t;
        int rp = e0g + n0 + t + excl;  // edges before n + self-loops before n
        if (n < N) {
            row_ptr[n] = rp;
            csr_src[rp] = n << 7;  // self-loop at slot 0 (byte offset)
        }
        lh[t] = rp + 1;  // cursor
    }
    __syncthreads();
    for (int e = e0c + t; e < e1c; e += 1024) {
        int p = pairs[e];
        int pos = atomicAdd(&lh[p & 255], 1);
        csr_src[pos] = (p >> 8) << 7;  // s<<7
    }
    if (b == 0 && t == 0) row_ptr[N] = Etot;
}

// ====== fused MFMA GEMM + pack (COUT=64): x[N,K] @ W[K,64] -> hrec/asb/adb ==

template <int K>
__global__ __launch_bounds__(256) void gemm_pack8_k(
    const float* __restrict__ x, const float* __restrict__ W,
    const float* __restrict__ a_src, const float* __restrict__ a_dst,
    char* __restrict__ hrec, float* __restrict__ asb,
    float* __restrict__ adb, int N) {
    constexpr int NT = 4;
    constexpr int KT = K / 32;
    constexpr size_t WF_BYTES = (size_t)KT * NT * 64 * 8 * sizeof(short);
    constexpr size_t H_BYTES = (size_t)64 * 65 * sizeof(float);
    __shared__ alignas(16) char smem[WF_BYTES > H_BYTES ? WF_BYTES : H_BYTES];
    short* Wf = (short*)smem;
    float* hL = (float*)smem;
    int tid = threadIdx.x;
    for (int f = tid; f < KT * NT * 64; f += 256) {
        int lane = f & 63;
        int ntk = f >> 6;
        int nt = ntk % NT, kt = ntk / NT;
        int q = lane >> 4, c = lane & 15;
        int n = nt * 16 + c;
        int k0 = kt * 32 + q * 8;
        short8 frag;
        #pragma unroll
        for (int j = 0; j < 8; ++j)
            frag[j] = (short)f2bf(W[(size_t)(k0 + j) * 64 + n]);
        *(short8*)&Wf[f * 8] = frag;
    }
    __syncthreads();
    int wave = tid >> 6, lane = tid & 63;
    int q = lane >> 4, c = lane & 15;
    int m0 = blockIdx.x * 64 + wave * 16;
    int arow = m0 + c;
    int arl = arow < N ? arow : N - 1;
    f32x4 acc[NT] = {};
    for (int kt = 0; kt < KT; ++kt) {
        const float* xp = x + (size_t)arl * K + kt * 32 + q * 8;
        float4 a0 = *(const float4*)xp;
        float4 a1 = *(const float4*)(xp + 4);
        float av[8] = {a0.x, a0.y, a0.z, a0.w, a1.x, a1.y, a1.z, a1.w};
        short8 af;
        #pragma unroll
        for (int j = 0; j < 8; ++j) af[j] = (short)f2bf(av[j]);
        #pragma unroll
        for (int nt = 0; nt < NT; ++nt) {
            short8 bf = *(const short8*)&Wf[((kt * NT + nt) * 64 + lane) * 8];
            acc[nt] = __builtin_amdgcn_mfma_f32_16x16x32_bf16(af, bf, acc[nt],
                                                              0, 0, 0);
        }
    }
    __syncthreads();  // all waves done reading Wf; reuse as hL
    int lrow = wave * 16 + q * 4;
    #pragma unroll
    for (int nt = 0; nt < NT; ++nt)
        #pragma unroll
        for (int reg = 0; reg < 4; ++reg)
            hL[(lrow + reg) * 65 + nt * 16 + c] = acc[nt][reg];
    __syncthreads();
    #pragma unroll
    for (int it = 0; it < 2; ++it) {
        int id = it * 256 + tid;  // 0..511 = (node 0..63) x (head 0..7)
        int ln = id >> 3, hd = id & 7;
        int gn = blockIdx.x * 64 + ln;
        if (gn >= N) continue;
        const float* hp = &hL[ln * 65 + hd * 8];
        float as = 0.f, ad = 0.f;
        float hv[8];
        #pragma unroll
        for (int j = 0; j < 8; ++j) {
            hv[j] = hp[j];
            as += hv[j] * a_src[hd * 8 + j];
            ad += hv[j] * a_dst[hd * 8 + j];
        }
        adb[gn * 8 + hd] = ad * LOG2E;
        asb[gn * 8 + hd] = as * LOG2E;
        unsigned short u[8];
        #pragma unroll
        for (int j = 0; j < 8; ++j) u[j] = f2bf(hv[j]);
        uint4 pk;
        pk.x = (unsigned)u[0] | ((unsigned)u[1] << 16);
        pk.y = (unsigned)u[2] | ((unsigned)u[3] << 16);
        pk.z = (unsigned)u[4] | ((unsigned)u[5] << 16);
        pk.w = (unsigned)u[6] | ((unsigned)u[7] << 16);
        *(uint4*)(hrec + (size_t)gn * 128 + hd * 16) = pk;
    }
}

// ====== fused MFMA GEMM + pack40 (layer 2): 128 B records, as at +80 ======

__global__ __launch_bounds__(256) void gemm_pack40_k(
    const float* __restrict__ x, const float* __restrict__ W,
    const float* __restrict__ a_src, const float* __restrict__ a_dst,
    char* __restrict__ rec40, float* __restrict__ adb, int N) {
    constexpr int K = 64, NT = 3, KT = 2;
    constexpr size_t WF_BYTES = (size_t)KT * NT * 64 * 8 * sizeof(short);
    constexpr size_t H_BYTES = (size_t)64 * 41 * sizeof(float);
    __shared__ alignas(16) char smem[WF_BYTES > H_BYTES ? WF_BYTES : H_BYTES];
    short* Wf = (short*)smem;
    float* hL = (float*)smem;
    int tid = threadIdx.x;
    for (int f = tid; f < KT * NT * 64; f += 256) {
        int lane = f & 63;
        int ntk = f >> 6;
        int nt = ntk % NT, kt = ntk / NT;
        int q = lane >> 4, c = lane & 15;
        int n = nt * 16 + c;
        int k0 = kt * 32 + q * 8;
        short8 frag;
        #pragma unroll
        for (int j = 0; j < 8; ++j) {
            float v = (n < 40) ? W[(size_t)(k0 + j) * 40 + n] : 0.f;
            frag[j] = (short)f2bf(v);
        }
        *(short8*)&Wf[f * 8] = frag;
    }
    __syncthreads();
    int wave = tid >> 6, lane = tid & 63;
    int q = lane >> 4, c = lane & 15;
    int m0 = blockIdx.x * 64 + wave * 16;
    int arow = m0 + c;
    int arl = arow < N ? arow : N - 1;
    f32x4 acc[NT] = {};
    for (int kt = 0; kt < KT; ++kt) {
        const float* xp = x + (size_t)arl * K + kt * 32 + q * 8;
        float4 a0 = *(const float4*)xp;
        float4 a1 = *(const float4*)(xp + 4);
        float av[8] = {a0.x, a0.y, a0.z, a0.w, a1.x, a1.y, a1.z, a1.w};
        short8 af;
        #pragma unroll
        for (int j = 0; j < 8; ++j) af[j] = (short)f2bf(av[j]);
        #pragma unroll
        for (int nt = 0; nt < NT; ++nt) {
            short8 bf = *(const short8*)&Wf[((kt * NT + nt) * 64 + lane) * 8];
            acc[nt] = __builtin_amdgcn_mfma_f32_16x16x32_bf16(af, bf, acc[nt],
                                                              0, 0, 0);
        }
    }
    __syncthreads();
    int lrow = wave * 16 + q * 4;
    #pragma unroll
    for (int nt = 0; nt < NT; ++nt) {
        int n = nt * 16 + c;
        if (n >= 40) continue;
        #pragma unroll
        for (int reg = 0; reg < 4; ++reg)
            hL[(lrow + reg) * 41 + n] = acc[nt][reg];
    }
    __syncthreads();
    // 4 threads per node compute pas/pad
    int ln = tid >> 2, sub = tid & 3;
    int gn = blockIdx.x * 64 + ln;
    float pas = 0.f, pad = 0.f;
    if (gn < N) {
        for (int j = sub; j < 40; j += 4) {
            float hv = hL[ln * 41 + j];
            pas += hv * a_src[j];
            pad += hv * a_dst[j];
        }
    }
    pas += __shfl_xor(pas, 1); pas += __shfl_xor(pas, 2);
    pad += __shfl_xor(pad, 1); pad += __shfl_xor(pad, 2);
    if (gn < N && sub == 0) {
        *(float*)(rec40 + (size_t)gn * 128 + 80) = pas * LOG2E;
        adb[gn] = pad * LOG2E;
    }
    // write bf16 h, stride 128 B
    for (int i = tid; i < 64 * 40; i += 256) {
        int n2 = i / 40, ch = i % 40;
        int g2 = blockIdx.x * 64 + n2;
        if (g2 < N)
            *(unsigned short*)(rec40 + (size_t)g2 * 128 + ch * 2) =
                f2bf(hL[n2 * 41 + ch]);
    }
}

// ======= aggr64: 8 edges per gather (16 B/lane dwordx4) ====================
// Lane layout in fma phase: g=lane>>3 picks edge j+g, head=lane&7 picks the
// 16B head chunk. Weights in LDS [head*68+edge] (<=2-way banks, 0 conflicts).
// Final combine: shfl_xor over masks 8/16/32. Padded edges have w==0.

#define G64(SUF, JB)                                                          \
    int sv##SUF = __builtin_amdgcn_ds_bpermute((JB) * 4 + g4, sv);            \
    float w##SUF = wb[(JB) + wofs];                                           \
    uint4 hv##SUF =                                                           \
        *(const uint4*)(gbase + (size_t)(unsigned)sv##SUF + hoff);

#define FMA8(SUF, LS)                                                         \
    LS;                                                                       \
    acc0 = fmaf(w##SUF, __uint_as_float(hv##SUF.x << 16), acc0);              \
    acc1 = fmaf(w##SUF, __uint_as_float(hv##SUF.x & 0xFFFF0000u), acc1);      \
    acc2 = fmaf(w##SUF, __uint_as_float(hv##SUF.y << 16), acc2);              \
    acc3 = fmaf(w##SUF, __uint_as_float(hv##SUF.y & 0xFFFF0000u), acc3);      \
    acc4 = fmaf(w##SUF, __uint_as_float(hv##SUF.z << 16), acc4);              \
    acc5 = fmaf(w##SUF, __uint_as_float(hv##SUF.z & 0xFFFF0000u), acc5);      \
    acc6 = fmaf(w##SUF, __uint_as_float(hv##SUF.w << 16), acc6);              \
    acc7 = fmaf(w##SUF, __uint_as_float(hv##SUF.w & 0xFFFF0000u), acc7);

__global__ __launch_bounds__(256) void aggr64_k(
    const char* __restrict__ hrec, const float* __restrict__ asb,
    const float* __restrict__ adb, const int* __restrict__ row_ptr,
    const int* __restrict__ csr_src, const float* __restrict__ bias,
    float* __restrict__ out, int N) {
    __shared__ float wlds[4 * 544];  // 4 waves x 8 heads x 68
    int wave = threadIdx.x >> 6;
    int node = blockIdx.x * 4 + wave;
    if (node >= N) return;
    int lane = threadIdx.x & 63;
    const char* gbase = hrec;
    float* wb = wlds + wave * 544;
    int g4 = (lane >> 3) * 4;                      // bpermute byte addr part
    int hoff = (lane & 7) * 16;                    // byte offset in record
    int wofs = (lane & 7) * 68 + (lane >> 3);      // w read offset
    int beg = row_ptr[node], end = row_ptr[node + 1];
    float4 adv0 = *(const float4*)(adb + (size_t)node * 8);
    float4 adv1 = *(const float4*)(adb + (size_t)node * 8 + 4);
    float acc0 = 0.f, acc1 = 0.f, acc2 = 0.f, acc3 = 0.f;
    float acc4 = 0.f, acc5 = 0.f, acc6 = 0.f, acc7 = 0.f;
    float lpart = 0.f;
    for (int i0 = beg; i0 < end; i0 += 64) {
        int tail = end - i0;
        int sv = csr_src[i0 + (lane < tail ? lane : 0)];  // byte offset s<<7
        int cnt = tail < 64 ? tail : 64;
        // ---- weight phase: this lane's edge, all 8 heads ----
        {
            const float* asp =
                (const float*)((const char*)asb + (((unsigned)sv) >> 2));
            float4 s0 = *(const float4*)asp;
            float4 s1 = *(const float4*)(asp + 4);
            float w0 = s0.x + adv0.x; w0 = fmaxf(w0, NEG_SLOPE * w0); w0 = fexp2(w0);
            float w1 = s0.y + adv0.y; w1 = fmaxf(w1, NEG_SLOPE * w1); w1 = fexp2(w1);
            float w2 = s0.z + adv0.z; w2 = fmaxf(w2, NEG_SLOPE * w2); w2 = fexp2(w2);
            float w3 = s0.w + adv0.w; w3 = fmaxf(w3, NEG_SLOPE * w3); w3 = fexp2(w3);
            float w4 = s1.x + adv1.x; w4 = fmaxf(w4, NEG_SLOPE * w4); w4 = fexp2(w4);
            float w5 = s1.y + adv1.y; w5 = fmaxf(w5, NEG_SLOPE * w5); w5 = fexp2(w5);
            float w6 = s1.z + adv1.z; w6 = fmaxf(w6, NEG_SLOPE * w6); w6 = fexp2(w6);
            float w7 = s1.w + adv1.w; w7 = fmaxf(w7, NEG_SLOPE * w7); w7 = fexp2(w7);
            if (lane >= cnt) {  // zero-pad
                w0 = 0.f; w1 = 0.f; w2 = 0.f; w3 = 0.f;
                w4 = 0.f; w5 = 0.f; w6 = 0.f; w7 = 0.f;
            }
            wb[lane]          = w0;
            wb[68 + lane]     = w1;
            wb[2 * 68 + lane] = w2;
            wb[3 * 68 + lane] = w3;
            wb[4 * 68 + lane] = w4;
            wb[5 * 68 + lane] = w5;
            wb[6 * 68 + lane] = w6;
            wb[7 * 68 + lane] = w7;
        }
        // ---- fma phase: 8 edges per gather (lpart += w, per subset) ----
        int j = 0;
        for (; j + 32 <= cnt; j += 32) {
            G64(A, j) G64(B, j + 8) G64(C, j + 16) G64(D, j + 24)
            FMA8(A, lpart += wA) FMA8(B, lpart += wB)
            FMA8(C, lpart += wC) FMA8(D, lpart += wD)
        }
        for (; j < cnt; j += 8) {
            G64(A, j)
            FMA8(A, lpart += wA)
        }
    }
    // combine the 8 edge-subsets per head (lanes differing in bits 3..5)
    #pragma unroll
    for (int m = 8; m <= 32; m <<= 1) {
        acc0 += __shfl_xor(acc0, m);
        acc1 += __shfl_xor(acc1, m);
        acc2 += __shfl_xor(acc2, m);
        acc3 += __shfl_xor(acc3, m);
        acc4 += __shfl_xor(acc4, m);
        acc5 += __shfl_xor(acc5, m);
        acc6 += __shfl_xor(acc6, m);
        acc7 += __shfl_xor(acc7, m);
        lpart += __shfl_xor(lpart, m);
    }
    if (lane < 8) {  // lane = head; writes channels head*8..head*8+7
        float denom = lpart + 1e-16f;
        const float4 b0 = *(const float4*)(bias + lane * 8);
        const float4 b1 = *(const float4*)(bias + lane * 8 + 4);
        float4 o0, o1;
        o0.x = acc0 / denom + b0.x;
        o0.y = acc1 / denom + b0.y;
        o0.z = acc2 / denom + b0.z;
        o0.w = acc3 / denom + b0.w;
        o1.x = acc4 / denom + b1.x;
        o1.y = acc5 / denom + b1.y;
        o1.z = acc6 / denom + b1.z;
        o1.w = acc7 / denom + b1.w;
        float* op = out + (size_t)node * 64 + lane * 8;
        *(float4*)op = o0;
        *(float4*)(op + 4) = o1;
    }
}

// ======= aggr40: 8 edges per gather; 5 active 8-ch chunks ==================
// l comes from the weight phase (per-lane own edge, full-wave reduce).

#define G40(SUF, JB)                                                          \
    int sv##SUF = __builtin_amdgcn_ds_bpermute((JB) * 4 + g4, sv);            \
    float w##SUF = wb[(JB) + gof];                                            \
    uint4 hv##SUF =                                                           \
        *(const uint4*)(gbase + (size_t)(unsigned)sv##SUF + hoff);

__global__ __launch_bounds__(256) void aggr40_k(
    const char* __restrict__ rec40, const float* __restrict__ adb,
    const int* __restrict__ row_ptr, const int* __restrict__ csr_src,
    const float* __restrict__ bias, float* __restrict__ out, int N) {
    __shared__ float wlds[4 * 104];  // per wave: 64 w + 40 epi
    int wave = threadIdx.x >> 6;
    int node = blockIdx.x * 4 + wave;
    if (node >= N) return;
    int lane = threadIdx.x & 63;
    const char* gbase = rec40;
    float* wb = wlds + wave * 104;
    float* epi = wb + 64;
    int g4 = (lane >> 3) * 4;
    int sub = lane & 7;
    int hoff = (sub < 5 ? sub : 0) * 16;
    int gof = lane >> 3;
    int beg = row_ptr[node], end = row_ptr[node + 1];
    float ad = adb[node];
    float acc0 = 0.f, acc1 = 0.f, acc2 = 0.f, acc3 = 0.f;
    float acc4 = 0.f, acc5 = 0.f, acc6 = 0.f, acc7 = 0.f;
    float lpart = 0.f;
    for (int i0 = beg; i0 < end; i0 += 64) {
        int tail = end - i0;
        int sv = csr_src[i0 + (lane < tail ? lane : 0)];  // byte offset s<<7
        int cnt = tail < 64 ? tail : 64;
        // ---- weight phase: lane computes its own edge's weight ----
        float as = *(const float*)(rec40 + (size_t)(unsigned)sv + 80);
        float v = as + ad;
        v = fmaxf(v, NEG_SLOPE * v);
        float wv = fexp2(v);
        wv = (lane < cnt) ? wv : 0.f;
        lpart += wv;
        wb[lane] = wv;
        // ---- fma phase: 8 edges per gather (w already counted in lpart) ----
        int j = 0;
        for (; j + 32 <= cnt; j += 32) {
            G40(A, j) G40(B, j + 8) G40(C, j + 16) G40(D, j + 24)
            FMA8(A, ) FMA8(B, ) FMA8(C, ) FMA8(D, )
        }
        for (; j < cnt; j += 8) {
            G40(A, j)
            FMA8(A, )
        }
    }
    // reduce acc over the 8 edge-subsets (lanes sharing sub)
    #pragma unroll
    for (int m = 8; m <= 32; m <<= 1) {
        acc0 += __shfl_xor(acc0, m);
        acc1 += __shfl_xor(acc1, m);
        acc2 += __shfl_xor(acc2, m);
        acc3 += __shfl_xor(acc3, m);
        acc4 += __shfl_xor(acc4, m);
        acc5 += __shfl_xor(acc5, m);
        acc6 += __shfl_xor(acc6, m);
        acc7 += __shfl_xor(acc7, m);
    }
    // l: full-wave reduce of weight-phase partials
    #pragma unroll
    for (int off = 32; off > 0; off >>= 1) lpart += __shfl_xor(lpart, off);
    float l = lpart;
    // redistribute: lanes 0..4 (g==0, sub<5) hold sums for channels sub*8+k
    if (lane < 5) {
        *(float4*)&epi[lane * 8] = make_float4(acc0, acc1, acc2, acc3);
        *(float4*)&epi[lane * 8 + 4] = make_float4(acc4, acc5, acc6, acc7);
    }
    float accv = (lane < 40) ? epi[lane] : 0.f;
    // fused bias + log_softmax over the 40 class lanes
    float val = accv / (l + 1e-16f) + ((lane < 40) ? bias[lane] : 0.f);
    float mval = (lane < 40) ? val : -1e30f;
    #pragma unroll
    for (int off = 32; off > 0; off >>= 1)
        mval = fmaxf(mval, __shfl_xor(mval, off));
    float ex = (lane < 40) ? __expf(val - mval) : 0.f;
    #pragma unroll
    for (int off = 32; off > 0; off >>= 1) ex += __shfl_xor(ex, off);
    if (lane < 40)
        out[(size_t)node * 40 + lane] = val - mval - __logf(ex);
}

// =================== launch ===================

extern "C" void kernel_launch(void* const* d_in, const int* in_sizes, int n_in,
                              void* d_out, int out_size, void* d_ws,
                              size_t ws_size, hipStream_t stream) {
    const float* features = (const float*)d_in[0];
    const int* edge_index = (const int*)d_in[1];
    const float* W0 = (const float*)d_in[2];
    const float* as0 = (const float*)d_in[3];
    const float* ad0 = (const float*)d_in[4];
    const float* b0 = (const float*)d_in[5];
    const float* W1 = (const float*)d_in[6];
    const float* as1 = (const float*)d_in[7];
    const float* ad1 = (const float*)d_in[8];
    const float* b1 = (const float*)d_in[9];
    const float* W2 = (const float*)d_in[10];
    const float* as2 = (const float*)d_in[11];
    const float* ad2 = (const float*)d_in[12];
    const float* b2 = (const float*)d_in[13];

    int N = in_sizes[0] / 256;
    int E = in_sizes[1] / 2;
    int Etot = E + N;
    int nbuck = (N + 255) >> 8;  // 256-node buckets (<= MAXBUCK)
    const int* srcs = edge_index;
    const int* dsts = edge_index + E;

    // workspace layout
    float* ws = (float*)d_ws;
    float* Hbuf = ws;                              // N*64 floats (pairs scratch)
    float* Abuf = Hbuf + (size_t)N * 64;           // N*64 floats
    float* adb  = Abuf + (size_t)N * 64;           // N*8
    float* asb  = adb + (size_t)N * 8;             // N*8
    char* hrec  = (char*)(asb + (size_t)N * 8);    // N*128 bytes
    int* row_ptr = (int*)(hrec + (size_t)N * 128); // N+1
    int* bcurE   = row_ptr + (N + 2);              // MAXBUCK
    int* bstart  = bcurE + MAXBUCK;                // MAXBUCK
    int* csr_src = bstart + MAXBUCK;               // Etot
    int* pairs   = (int*)Hbuf;                     // nbuck*CAP <= N*64

    const int B = 256;
    int gAg = (N + 3) / 4;
    int gGm = (N + 63) / 64;
    int gSc = (E + EPB - 1) / EPB;
    int gBi = (nbuck + 255) / 256;

    // ---------- CSR build (256-node buckets, fixed-CAP segments) ----------
    binit_k<<<gBi, B, 0, stream>>>(bcurE, nbuck);
    bscatter_k<<<gSc, 1024, 0, stream>>>(srcs, dsts, bcurE, pairs, E, nbuck);
    bscan_k<<<1, 512, 0, stream>>>(bcurE, bstart, nbuck);
    bucket_sort_k<<<nbuck, 1024, 0, stream>>>(pairs, bcurE, bstart, row_ptr,
                                              csr_src, N, Etot);

    // ---------------- layer 0 ----------------
    gemm_pack8_k<256><<<gGm, B, 0, stream>>>(features, W0, as0, ad0, hrec,
                                             asb, adb, N);
    aggr64_k<<<gAg, B, 0, stream>>>(hrec, asb, adb, row_ptr, csr_src, b0,
                                    Abuf, N);

    // ---------------- layer 1 ----------------
    gemm_pack8_k<64><<<gGm, B, 0, stream>>>(Abuf, W1, as1, ad1, hrec, asb,
                                            adb, N);
    aggr64_k<<<gAg, B, 0, stream>>>(hrec, asb, adb, row_ptr, csr_src, b1,
                                    Abuf, N);

    // ---------------- layer 2 ----------------
    gemm_pack40_k<<<gGm, B, 0, stream>>>(Abuf, W2, as2, ad2, hrec, adb, N);
    aggr40_k<<<gAg, B, 0, stream>>>(hrec, adb, row_ptr, csr_src, b2,
                                    (float*)d_out, N);
}